// Round 1
// baseline (974.662 us; speedup 1.0000x reference)
//
#include <hip/hip_runtime.h>

// RGCN layer: out = x@W_self + b_self + sum_t segment_mean_t(x[src])@W[t] + (deg_t>0)*b[t]
// Strategy: build CSR by (etype,dst) with int atomics only, then one fused kernel:
//   per 64-node tile: aggregate mean(x[src]) into LDS -> tiled fp32 vector GEMM
//   (K = 128 per pass, 5 passes: 4 etypes + self), bias gated on deg>0.
// No feature atomics, no 410 MB intermediate; ws use ~17.6 MB.

namespace {

constexpr int N  = 200000;  // nodes
constexpr int T  = 4;       // etypes
constexpr int E  = 500000;  // edges per etype
constexpr int D  = 128;     // d_in == d_out
constexpr int NT = 64;      // nodes per block tile
constexpr int KC = 32;      // k-chunk staged in LDS

__global__ void k_zero(int* __restrict__ cnt, int* __restrict__ cursor) {
  int i = blockIdx.x * 256 + threadIdx.x;
  if (i < T * N) cnt[i] = 0;
  if (i == 0) *cursor = 0;
}

__global__ void k_count(const int* __restrict__ dst, int* __restrict__ cnt) {
  int i = blockIdx.x * 256 + threadIdx.x;
  if (i >= T * E) return;
  int t = i / E;
  atomicAdd(&cnt[t * N + dst[i]], 1);
}

// Exclusive offsets via block scan + one global-cursor atomic per block.
// Slot ranges are disjoint & correctly sized; inter-block order is irrelevant.
__global__ void k_offsets(const int* __restrict__ cnt, int* __restrict__ offs,
                          int* __restrict__ cur, int* __restrict__ cursor) {
  __shared__ int s[256];
  __shared__ int base;
  int tid = threadIdx.x;
  int i = blockIdx.x * 256 + tid;
  int c = (i < T * N) ? cnt[i] : 0;
  s[tid] = c;
  __syncthreads();
  for (int d = 1; d < 256; d <<= 1) {   // Hillis-Steele inclusive scan
    int v = (tid >= d) ? s[tid - d] : 0;
    __syncthreads();
    s[tid] += v;
    __syncthreads();
  }
  if (tid == 255) base = atomicAdd(cursor, s[255]);
  __syncthreads();
  if (i < T * N) {
    int e = base + s[tid] - c;  // exclusive
    offs[i] = e;
    cur[i]  = e;
  }
}

__global__ void k_scatter(const int* __restrict__ src, const int* __restrict__ dst,
                          int* __restrict__ cur, int* __restrict__ eid) {
  int i = blockIdx.x * 256 + threadIdx.x;
  if (i >= T * E) return;
  int t = i / E;
  int pos = atomicAdd(&cur[t * N + dst[i]], 1);
  eid[pos] = src[i];
}

// Fused aggregate + GEMM. 256 threads, 64-node tile, 128 out features.
// LDS: a_s 32 KB + w_s 16 KB = 48 KB -> 3 blocks/CU (12 waves/CU).
__global__ __launch_bounds__(256, 3) void k_fused(
    const float* __restrict__ x, const float* __restrict__ W,
    const float* __restrict__ b, const float* __restrict__ Wself,
    const float* __restrict__ bself, const int* __restrict__ cnt,
    const int* __restrict__ offs, const int* __restrict__ eid,
    float* __restrict__ out) {
  __shared__ __align__(16) float a_s[NT * D];  // 64 x 128 staged features
  __shared__ __align__(16) float w_s[KC * D];  // 32 x 128 W chunk

  const int tid  = threadIdx.x;
  const int nb   = blockIdx.x * NT;
  const int fcol = tid & 31;   // float4 column 0..31 (f = fcol*4..fcol*4+3)
  const int rrow = tid >> 5;   // row group 0..7 (rows rrow+8j)
  const int ln   = tid >> 2;   // local node 0..63 (staging)
  const int q    = tid & 3;    // quarter-row lane (f = q*32..q*32+31)

  float4 acc[8];
#pragma unroll
  for (int j = 0; j < 8; ++j) acc[j] = make_float4(0.f, 0.f, 0.f, 0.f);

  for (int pass = 0; pass < 5; ++pass) {
    const bool self = (pass == 4);
    const int t = pass;

    // ---- stage a_s: mean-aggregated x over in-edges of etype t (or x itself)
    {
      float4 r[8];
#pragma unroll
      for (int i = 0; i < 8; ++i) r[i] = make_float4(0.f, 0.f, 0.f, 0.f);
      const int node = nb + ln;
      if (self) {
        const float4* xr = (const float4*)(x + node * D + q * 32);
#pragma unroll
        for (int i = 0; i < 8; ++i) r[i] = xr[i];
      } else {
        const int base = offs[t * N + node];
        const int deg  = cnt[t * N + node];
        for (int e = 0; e < deg; ++e) {
          const int sidx = eid[base + e];
          const float4* xr = (const float4*)(x + sidx * D + q * 32);
#pragma unroll
          for (int i = 0; i < 8; ++i) {
            float4 v = xr[i];
            r[i].x += v.x; r[i].y += v.y; r[i].z += v.z; r[i].w += v.w;
          }
        }
        const float inv = (deg > 0) ? (1.0f / (float)deg) : 0.0f;
#pragma unroll
        for (int i = 0; i < 8; ++i) {
          r[i].x *= inv; r[i].y *= inv; r[i].z *= inv; r[i].w *= inv;
        }
      }
      float4* as4 = (float4*)(a_s + ln * D + q * 32);
#pragma unroll
      for (int i = 0; i < 8; ++i) as4[i] = r[i];
    }
    __syncthreads();

    // ---- tiled GEMM: acc[64x128] += a_s[64x128] @ Wt[128x128]
    const float* Wt = self ? Wself : (W + t * D * D);
    for (int kc = 0; kc < D; kc += KC) {
      {
        const float4* wg  = (const float4*)(Wt + kc * D);
        float4* ws4 = (float4*)w_s;
#pragma unroll
        for (int i = 0; i < (KC * D / 4) / 256; ++i)
          ws4[i * 256 + tid] = wg[i * 256 + tid];
      }
      __syncthreads();
#pragma unroll
      for (int k = 0; k < KC; k += 4) {
        const float4 w0 = *(const float4*)(w_s + (k + 0) * D + fcol * 4);
        const float4 w1 = *(const float4*)(w_s + (k + 1) * D + fcol * 4);
        const float4 w2 = *(const float4*)(w_s + (k + 2) * D + fcol * 4);
        const float4 w3 = *(const float4*)(w_s + (k + 3) * D + fcol * 4);
#pragma unroll
        for (int j = 0; j < 8; ++j) {
          const float4 a4 = *(const float4*)(a_s + (rrow + 8 * j) * D + kc + k);
          acc[j].x += a4.x * w0.x; acc[j].y += a4.x * w0.y; acc[j].z += a4.x * w0.z; acc[j].w += a4.x * w0.w;
          acc[j].x += a4.y * w1.x; acc[j].y += a4.y * w1.y; acc[j].z += a4.y * w1.z; acc[j].w += a4.y * w1.w;
          acc[j].x += a4.z * w2.x; acc[j].y += a4.z * w2.y; acc[j].z += a4.z * w2.z; acc[j].w += a4.z * w2.w;
          acc[j].x += a4.w * w3.x; acc[j].y += a4.w * w3.y; acc[j].z += a4.w * w3.z; acc[j].w += a4.w * w3.w;
        }
      }
      __syncthreads();
    }

    // ---- bias: b[t] only where deg>0; b_self always
    const float* bt = self ? bself : (b + t * D);
    const float4 b4 = *(const float4*)(bt + fcol * 4);
#pragma unroll
    for (int j = 0; j < 8; ++j) {
      bool add = self || (cnt[t * N + nb + rrow + 8 * j] > 0);
      if (add) {
        acc[j].x += b4.x; acc[j].y += b4.y; acc[j].z += b4.z; acc[j].w += b4.w;
      }
    }
  }

  // ---- epilogue: coalesced float4 stores
#pragma unroll
  for (int j = 0; j < 8; ++j) {
    *(float4*)(out + (nb + rrow + 8 * j) * D + fcol * 4) = acc[j];
  }
}

}  // namespace

extern "C" void kernel_launch(void* const* d_in, const int* in_sizes, int n_in,
                              void* d_out, int out_size, void* d_ws, size_t ws_size,
                              hipStream_t stream) {
  const float* x     = (const float*)d_in[0];
  const float* W     = (const float*)d_in[1];
  const float* b     = (const float*)d_in[2];
  const float* Wself = (const float*)d_in[3];
  const float* bself = (const float*)d_in[4];
  const int*   src   = (const int*)d_in[5];
  const int*   dst   = (const int*)d_in[6];
  float* out = (float*)d_out;

  // ws layout (ints): cnt[T*N] | offs[T*N] | cur[T*N] | eid[T*E] | cursor[1]
  int* cnt    = (int*)d_ws;
  int* offs   = cnt + T * N;
  int* cur    = offs + T * N;
  int* eid    = cur + T * N;
  int* cursor = eid + T * E;

  k_zero<<<(T * N + 256) / 256, 256, 0, stream>>>(cnt, cursor);
  k_count<<<(T * E + 255) / 256, 256, 0, stream>>>(dst, cnt);
  k_offsets<<<(T * N + 255) / 256, 256, 0, stream>>>(cnt, offs, cur, cursor);
  k_scatter<<<(T * E + 255) / 256, 256, 0, stream>>>(src, dst, cur, eid);
  k_fused<<<N / NT, 256, 0, stream>>>(x, W, b, Wself, bself, cnt, offs, eid, out);
}

// Round 2
// 692.372 us; speedup vs baseline: 1.4077x; 1.4077x over previous
//
#include <hip/hip_runtime.h>
#include <hip/hip_bf16.h>

// RGCN layer: out = x@W_self + b_self + sum_t [ mean_t(x[src]) @ W[t] + (deg_t>0)*b[t] ]
// v2: CSR build (int atomics only) -> fused kernel with bf16 MFMA GEMM.
//   - k_prep_w packs W^T (and W_self^T) to bf16 in ws: Wt[p][n][k], p=0..4.
//   - k_fused: per 64-node tile: mean-aggregate x into LDS (bf16, stride 136),
//     stage W^T chunk, 16x16x32 bf16 MFMA accumulating fp32 across 5 passes.

namespace {

constexpr int N  = 200000;  // nodes
constexpr int T  = 4;       // etypes
constexpr int E  = 500000;  // edges per etype
constexpr int D  = 128;     // d_in == d_out
constexpr int NT = 64;      // nodes per block tile
constexpr int AS = 136;     // padded LDS row stride (bf16 elems): 2-way bank alias only

typedef __bf16 bf16x8 __attribute__((ext_vector_type(8)));
typedef float  f32x4  __attribute__((ext_vector_type(4)));

__global__ void k_zero(int* __restrict__ cnt, int* __restrict__ cursor) {
  int i = blockIdx.x * 256 + threadIdx.x;
  if (i < T * N) cnt[i] = 0;
  if (i == 0) *cursor = 0;
}

__global__ void k_count(const int* __restrict__ dst, int* __restrict__ cnt) {
  int i = blockIdx.x * 256 + threadIdx.x;
  if (i >= T * E) return;
  int t = i / E;
  atomicAdd(&cnt[t * N + dst[i]], 1);
}

// Exclusive offsets via block scan + one global-cursor atomic per block.
__global__ void k_offsets(const int* __restrict__ cnt, int* __restrict__ offs,
                          int* __restrict__ cur, int* __restrict__ cursor) {
  __shared__ int s[256];
  __shared__ int base;
  int tid = threadIdx.x;
  int i = blockIdx.x * 256 + tid;
  int c = (i < T * N) ? cnt[i] : 0;
  s[tid] = c;
  __syncthreads();
  for (int d = 1; d < 256; d <<= 1) {
    int v = (tid >= d) ? s[tid - d] : 0;
    __syncthreads();
    s[tid] += v;
    __syncthreads();
  }
  if (tid == 255) base = atomicAdd(cursor, s[255]);
  __syncthreads();
  if (i < T * N) {
    int e = base + s[tid] - c;
    offs[i] = e;
    cur[i]  = e;
  }
}

__global__ void k_scatter(const int* __restrict__ src, const int* __restrict__ dst,
                          int* __restrict__ cur, int* __restrict__ eid) {
  int i = blockIdx.x * 256 + threadIdx.x;
  if (i >= T * E) return;
  int t = i / E;
  int pos = atomicAdd(&cur[t * N + dst[i]], 1);
  eid[pos] = src[i];
}

// Pack W^T to bf16: wt[p][n][k] = (p<4 ? W[p][k][n] : Wself[k][n]).
__global__ void k_prep_w(const float* __restrict__ W, const float* __restrict__ Wself,
                         __bf16* __restrict__ wt) {
  int i = blockIdx.x * 256 + threadIdx.x;  // 5*128*128 = 81920
  if (i >= 5 * D * D) return;
  int p   = i >> 14;
  int rem = i & 16383;
  int n   = rem >> 7;
  int k   = rem & 127;
  float v = (p < 4) ? W[(p * D + k) * D + n] : Wself[k * D + n];
  wt[i] = (__bf16)v;
}

// Fused aggregate + bf16 MFMA GEMM. 256 threads (4 waves), 64-node tile.
// LDS: a_s 17408 B + w_s 34816 B = 52224 B -> 3 blocks/CU.
__global__ __launch_bounds__(256, 3) void k_fused(
    const float* __restrict__ x, const __bf16* __restrict__ wt,
    const float* __restrict__ b, const float* __restrict__ bself,
    const int* __restrict__ cnt, const int* __restrict__ offs,
    const int* __restrict__ eid, float* __restrict__ out) {
  __shared__ __align__(16) __bf16 a_s[NT * AS];   // 64 rows (nodes) x 128 k, stride 136
  __shared__ __align__(16) __bf16 w_s[D * AS];    // 128 rows (n)    x 128 k, stride 136

  const int tid  = threadIdx.x;
  const int nb   = blockIdx.x * NT;
  const int wv   = tid >> 6;   // wave 0..3 -> rows 16*wv..16*wv+15
  const int lane = tid & 63;
  const int quad = lane >> 4;  // 0..3
  const int l16  = lane & 15;
  const int ln   = tid >> 2;   // staging node 0..63
  const int q    = tid & 3;    // staging k-quarter: k = q*32 .. q*32+31

  f32x4 acc[8];
#pragma unroll
  for (int ct = 0; ct < 8; ++ct) acc[ct] = (f32x4){0.f, 0.f, 0.f, 0.f};

  for (int pass = 0; pass < 5; ++pass) {
    const bool self = (pass == 4);

    // ---- stage w_s: 32 KB bf16 W^T chunk (issue first; overlaps gather latency)
    {
      const __bf16* wsrc = wt + pass * D * D;
#pragma unroll
      for (int c = 0; c < 8; ++c) {
        int idx  = c * 256 + tid;       // 0..2047 16B chunks
        int row  = idx >> 4;
        int col8 = (idx & 15) * 8;
        *(bf16x8*)(w_s + row * AS + col8) =
            *(const bf16x8*)(wsrc + row * D + col8);
      }
    }

    // ---- stage a_s: mean-aggregated x (fp32 accumulate -> bf16 store)
    {
      float4 r[8];
#pragma unroll
      for (int i = 0; i < 8; ++i) r[i] = make_float4(0.f, 0.f, 0.f, 0.f);
      const int node = nb + ln;
      if (self) {
        const float4* xr = (const float4*)(x + node * D + q * 32);
#pragma unroll
        for (int i = 0; i < 8; ++i) r[i] = xr[i];
      } else {
        const int base = offs[pass * N + node];
        const int deg  = cnt[pass * N + node];
        for (int e = 0; e < deg; ++e) {
          const int sidx = eid[base + e];
          const float4* xr = (const float4*)(x + sidx * D + q * 32);
#pragma unroll
          for (int i = 0; i < 8; ++i) {
            float4 v = xr[i];
            r[i].x += v.x; r[i].y += v.y; r[i].z += v.z; r[i].w += v.w;
          }
        }
        const float inv = (deg > 0) ? (1.0f / (float)deg) : 0.0f;
#pragma unroll
        for (int i = 0; i < 8; ++i) {
          r[i].x *= inv; r[i].y *= inv; r[i].z *= inv; r[i].w *= inv;
        }
      }
      __bf16* arow = a_s + ln * AS + q * 32;
#pragma unroll
      for (int g = 0; g < 4; ++g) {
        bf16x8 v;
        v[0] = (__bf16)r[2 * g].x;     v[1] = (__bf16)r[2 * g].y;
        v[2] = (__bf16)r[2 * g].z;     v[3] = (__bf16)r[2 * g].w;
        v[4] = (__bf16)r[2 * g + 1].x; v[5] = (__bf16)r[2 * g + 1].y;
        v[6] = (__bf16)r[2 * g + 1].z; v[7] = (__bf16)r[2 * g + 1].w;
        *(bf16x8*)(arow + g * 8) = v;
      }
    }
    __syncthreads();

    // ---- MFMA GEMM: acc[16 x 128 per wave] += a_s @ w_s^T-layout
    // A-frag: A[m=l16][k=quad*8+j]; B-frag: B[k=quad*8+j][n=l16] from wt[n][k].
#pragma unroll
    for (int ks = 0; ks < 4; ++ks) {
      bf16x8 af = *(const bf16x8*)(a_s + (16 * wv + l16) * AS + ks * 32 + quad * 8);
#pragma unroll
      for (int ct = 0; ct < 8; ++ct) {
        bf16x8 bfr = *(const bf16x8*)(w_s + (16 * ct + l16) * AS + ks * 32 + quad * 8);
        acc[ct] = __builtin_amdgcn_mfma_f32_16x16x32_bf16(af, bfr, acc[ct], 0, 0, 0);
      }
    }

    // ---- bias: b[t] gated on deg>0 per output row; b_self unconditional.
    // C/D layout: col = 16*ct + l16, row = 16*wv + quad*4 + reg.
    {
      const float* bt = self ? bself : (b + pass * D);
      bool rowon[4];
#pragma unroll
      for (int r = 0; r < 4; ++r) {
        rowon[r] = self ? true
                        : (cnt[pass * N + nb + 16 * wv + quad * 4 + r] > 0);
      }
#pragma unroll
      for (int ct = 0; ct < 8; ++ct) {
        float bv = bt[16 * ct + l16];
#pragma unroll
        for (int r = 0; r < 4; ++r) {
          if (rowon[r]) acc[ct][r] += bv;
        }
      }
    }
    __syncthreads();  // before next pass overwrites LDS
  }

  // ---- epilogue: scalar stores (16-lane 64B segments; L2 merges adjacent ct)
#pragma unroll
  for (int ct = 0; ct < 8; ++ct) {
#pragma unroll
    for (int r = 0; r < 4; ++r) {
      out[(nb + 16 * wv + quad * 4 + r) * D + 16 * ct + l16] = acc[ct][r];
    }
  }
}

}  // namespace

extern "C" void kernel_launch(void* const* d_in, const int* in_sizes, int n_in,
                              void* d_out, int out_size, void* d_ws, size_t ws_size,
                              hipStream_t stream) {
  const float* x     = (const float*)d_in[0];
  const float* W     = (const float*)d_in[1];
  const float* b     = (const float*)d_in[2];
  const float* Wself = (const float*)d_in[3];
  const float* bself = (const float*)d_in[4];
  const int*   src   = (const int*)d_in[5];
  const int*   dst   = (const int*)d_in[6];
  float* out = (float*)d_out;

  // ws layout (ints): cnt[T*N] | offs[T*N] | cur[T*N] | eid[T*E] | cursor |
  //                   pad | Wt bf16 [5*128*128]
  int* cnt    = (int*)d_ws;
  int* offs   = cnt + T * N;
  int* cur    = offs + T * N;
  int* eid    = cur + T * N;
  int* cursor = eid + T * E;
  __bf16* wtp = (__bf16*)(cursor + 4);  // 16B-ish aligned past cursor

  k_zero<<<(T * N + 256) / 256, 256, 0, stream>>>(cnt, cursor);
  k_count<<<(T * E + 255) / 256, 256, 0, stream>>>(dst, cnt);
  k_offsets<<<(T * N + 255) / 256, 256, 0, stream>>>(cnt, offs, cur, cursor);
  k_scatter<<<(T * E + 255) / 256, 256, 0, stream>>>(src, dst, cur, eid);
  k_prep_w<<<(5 * D * D + 255) / 256, 256, 0, stream>>>(W, Wself, wtp);
  k_fused<<<N / NT, 256, 0, stream>>>(x, wtp, b, bself, cnt, offs, eid, out);
}

// Round 3
// 546.132 us; speedup vs baseline: 1.7847x; 1.2678x over previous
//
#include <hip/hip_runtime.h>
#include <hip/hip_bf16.h>

// RGCN layer: out = x@W_self + b_self + sum_t [ mean_t(x[src]) @ W[t] + (deg_t>0)*b[t] ]
// v3: - x pre-converted to bf16 (xb) once per launch: halves the random gather bytes
//       (the measured bottleneck: 543 MB of L2-miss traffic at 2.2 TB/s, latency-bound).
//     - eid software-pipelined in the gather loop (prefetch next edge id).
//     - self-pass A-fragments read directly from xb (skips one stage+barrier).
//     - scatter de-atomized: rank captured from k_count's atomicAdd return.
//     - count + W-pack + x-convert fused into one launch.

namespace {

constexpr int N  = 200000;  // nodes
constexpr int T  = 4;       // etypes
constexpr int E  = 500000;  // edges per etype
constexpr int D  = 128;     // d_in == d_out
constexpr int NT = 64;      // nodes per block tile
constexpr int AS = 136;     // padded LDS row stride (bf16): 2-way bank alias only (free)

constexpr int CNT_B = (T * E + 255) / 256;      // 7813
constexpr int PX_B  = (N * D / 8) / 256;        // 12500 (exact)
constexpr int PW_B  = (5 * D * D / 8 + 255) / 256;  // 40

typedef __bf16 bf16x8 __attribute__((ext_vector_type(8)));
typedef float  f32x4  __attribute__((ext_vector_type(4)));

__global__ void k_zero(int* __restrict__ p, int n) {
  int i = blockIdx.x * 256 + threadIdx.x;
  if (i < n) p[i] = 0;
}

// Fused: edge count (+rank) | x fp32->bf16 | W^T pack to bf16.
template <bool XB>
__global__ void k_prep(const int* __restrict__ dst, int* __restrict__ cnt,
                       int* __restrict__ rank, const float* __restrict__ x,
                       __bf16* __restrict__ xb, const float* __restrict__ W,
                       const float* __restrict__ Wself, __bf16* __restrict__ wt) {
  const int bid = blockIdx.x;
  const int tid = threadIdx.x;
  if (bid < CNT_B) {
    int i = bid * 256 + tid;
    if (i < T * E) {
      int t = i / E;
      rank[i] = atomicAdd(&cnt[t * N + dst[i]], 1);
    }
  } else if (XB && bid < CNT_B + PX_B) {
    int i = (bid - CNT_B) * 256 + tid;  // one per 8 floats
    if (i < N * D / 8) {
      const float4* xs = (const float4*)(x + i * 8);
      float4 a = xs[0], c = xs[1];
      bf16x8 v;
      v[0] = (__bf16)a.x; v[1] = (__bf16)a.y; v[2] = (__bf16)a.z; v[3] = (__bf16)a.w;
      v[4] = (__bf16)c.x; v[5] = (__bf16)c.y; v[6] = (__bf16)c.z; v[7] = (__bf16)c.w;
      *(bf16x8*)(xb + i * 8) = v;
    }
  } else {
    int i = (bid - CNT_B - (XB ? PX_B : 0)) * 256 + tid;  // one per 8 wt elems
    if (i < 5 * D * D / 8) {
      int base = i * 8;
      int p = base >> 14, rem = base & 16383;
      int n = rem >> 7, k0 = rem & 127;
      const float* Wsrc = (p < 4) ? (W + (size_t)p * D * D) : Wself;  // [k][n]
      bf16x8 v;
#pragma unroll
      for (int j = 0; j < 8; ++j) v[j] = (__bf16)Wsrc[(k0 + j) * D + n];
      *(bf16x8*)(wt + base) = v;
    }
  }
}

// Exclusive offsets via block scan + one global-cursor atomic per block.
__global__ void k_offsets(const int* __restrict__ cnt, int* __restrict__ offs,
                          int* __restrict__ cursor) {
  __shared__ int s[256];
  __shared__ int base;
  int tid = threadIdx.x;
  int i = blockIdx.x * 256 + tid;
  int c = (i < T * N) ? cnt[i] : 0;
  s[tid] = c;
  __syncthreads();
  for (int d = 1; d < 256; d <<= 1) {
    int v = (tid >= d) ? s[tid - d] : 0;
    __syncthreads();
    s[tid] += v;
    __syncthreads();
  }
  if (tid == 255) base = atomicAdd(cursor, s[255]);
  __syncthreads();
  if (i < T * N) offs[i] = base + s[tid] - c;  // exclusive
}

// No atomics: pos = offs[bucket] + rank (rank recorded during count).
__global__ void k_scatter(const int* __restrict__ src, const int* __restrict__ dst,
                          const int* __restrict__ offs, const int* __restrict__ rank,
                          int* __restrict__ eid) {
  int i = blockIdx.x * 256 + threadIdx.x;
  if (i >= T * E) return;
  int t = i / E;
  int pos = offs[t * N + dst[i]] + rank[i];
  eid[pos] = src[i];
}

// Fused aggregate + bf16 MFMA GEMM. 256 threads (4 waves), 64-node tile.
// LDS: a_s 17408 B + w_s 34816 B = 52224 B -> 3 blocks/CU.
template <bool XB>
__global__ __launch_bounds__(256, 3) void k_fused(
    const float* __restrict__ x, const __bf16* __restrict__ xb,
    const __bf16* __restrict__ wt, const float* __restrict__ b,
    const float* __restrict__ bself, const int* __restrict__ cnt,
    const int* __restrict__ offs, const int* __restrict__ eid,
    float* __restrict__ out) {
  __shared__ __align__(16) __bf16 a_s[NT * AS];
  __shared__ __align__(16) __bf16 w_s[D * AS];

  const int tid  = threadIdx.x;
  const int nb   = blockIdx.x * NT;
  const int wv   = tid >> 6;
  const int lane = tid & 63;
  const int quad = lane >> 4;
  const int l16  = lane & 15;
  const int ln   = tid >> 2;   // staging node 0..63
  const int q    = tid & 3;    // staging k-quarter: k = q*32 .. q*32+31

  f32x4 acc[8];
#pragma unroll
  for (int ct = 0; ct < 8; ++ct) acc[ct] = (f32x4){0.f, 0.f, 0.f, 0.f};

  for (int pass = 0; pass < 5; ++pass) {
    const bool self = (pass == 4);

    // ---- stage w_s (issue first; overlaps gather latency)
    {
      const __bf16* wsrc = wt + pass * D * D;
#pragma unroll
      for (int c = 0; c < 8; ++c) {
        int idx  = c * 256 + tid;
        int row  = idx >> 4;
        int col8 = (idx & 15) * 8;
        *(bf16x8*)(w_s + row * AS + col8) = *(const bf16x8*)(wsrc + row * D + col8);
      }
    }

    // ---- stage a_s: mean-aggregated features (skipped for self-pass when XB)
    if (!(XB && self)) {
      float r[32];
#pragma unroll
      for (int i = 0; i < 32; ++i) r[i] = 0.f;
      const int node = nb + ln;
      if (self) {  // only reached when !XB
        const float4* xr = (const float4*)(x + node * D + q * 32);
#pragma unroll
        for (int i = 0; i < 8; ++i) {
          float4 v = xr[i];
          r[4 * i] = v.x; r[4 * i + 1] = v.y; r[4 * i + 2] = v.z; r[4 * i + 3] = v.w;
        }
      } else {
        const int base = offs[pass * N + node];
        const int deg  = cnt[pass * N + node];
        int nxt = (deg > 0) ? eid[base] : 0;
        for (int e = 0; e < deg; ++e) {
          const int sidx = nxt;
          nxt = eid[base + e + 1];  // prefetch; reads slack/next bucket on last iter (harmless)
          if (XB) {
            const bf16x8* xr = (const bf16x8*)(xb + sidx * D + q * 32);
            bf16x8 v0 = xr[0], v1 = xr[1], v2 = xr[2], v3 = xr[3];
#pragma unroll
            for (int j = 0; j < 8; ++j) {
              r[j]      += (float)v0[j];
              r[8 + j]  += (float)v1[j];
              r[16 + j] += (float)v2[j];
              r[24 + j] += (float)v3[j];
            }
          } else {
            const float4* xr = (const float4*)(x + sidx * D + q * 32);
#pragma unroll
            for (int i = 0; i < 8; ++i) {
              float4 v = xr[i];
              r[4 * i] += v.x; r[4 * i + 1] += v.y;
              r[4 * i + 2] += v.z; r[4 * i + 3] += v.w;
            }
          }
        }
        const float inv = (deg > 0) ? (1.0f / (float)deg) : 0.0f;
#pragma unroll
        for (int i = 0; i < 32; ++i) r[i] *= inv;
      }
      __bf16* arow = a_s + ln * AS + q * 32;
#pragma unroll
      for (int g = 0; g < 4; ++g) {
        bf16x8 v;
#pragma unroll
        for (int j = 0; j < 8; ++j) v[j] = (__bf16)r[8 * g + j];
        *(bf16x8*)(arow + g * 8) = v;
      }
    }
    __syncthreads();

    // ---- MFMA: acc[16 x 128 per wave] += A @ W^T-layout
    // A-frag: A[m=l16][k=quad*8+j]; B-frag: B[k=quad*8+j][n=l16] from wt[n][k].
#pragma unroll
    for (int ks = 0; ks < 4; ++ks) {
      bf16x8 af;
      if (XB && self) {
        af = *(const bf16x8*)(xb + (nb + 16 * wv + l16) * D + ks * 32 + quad * 8);
      } else {
        af = *(const bf16x8*)(a_s + (16 * wv + l16) * AS + ks * 32 + quad * 8);
      }
#pragma unroll
      for (int ct = 0; ct < 8; ++ct) {
        bf16x8 bfr = *(const bf16x8*)(w_s + (16 * ct + l16) * AS + ks * 32 + quad * 8);
        acc[ct] = __builtin_amdgcn_mfma_f32_16x16x32_bf16(af, bfr, acc[ct], 0, 0, 0);
      }
    }

    // ---- bias: b[t] gated on deg>0 per output row; b_self unconditional.
    // C/D layout: col = 16*ct + l16, row = 16*wv + quad*4 + reg.
    {
      const float* bt = self ? bself : (b + pass * D);
      bool rowon[4];
#pragma unroll
      for (int r = 0; r < 4; ++r) {
        rowon[r] = self ? true : (cnt[pass * N + nb + 16 * wv + quad * 4 + r] > 0);
      }
#pragma unroll
      for (int ct = 0; ct < 8; ++ct) {
        float bv = bt[16 * ct + l16];
#pragma unroll
        for (int r = 0; r < 4; ++r)
          if (rowon[r]) acc[ct][r] += bv;
      }
    }
    if (pass < 4) __syncthreads();  // guard LDS overwrite by next pass
  }

  // ---- epilogue: each store instr covers 4 full 64B lines (4 rows x 16 lanes)
#pragma unroll
  for (int ct = 0; ct < 8; ++ct) {
#pragma unroll
    for (int r = 0; r < 4; ++r) {
      out[(nb + 16 * wv + quad * 4 + r) * D + 16 * ct + l16] = acc[ct][r];
    }
  }
}

}  // namespace

extern "C" void kernel_launch(void* const* d_in, const int* in_sizes, int n_in,
                              void* d_out, int out_size, void* d_ws, size_t ws_size,
                              hipStream_t stream) {
  const float* x     = (const float*)d_in[0];
  const float* W     = (const float*)d_in[1];
  const float* b     = (const float*)d_in[2];
  const float* Wself = (const float*)d_in[3];
  const float* bself = (const float*)d_in[4];
  const int*   src   = (const int*)d_in[5];
  const int*   dst   = (const int*)d_in[6];
  float* out = (float*)d_out;

  // ws (ints): cnt[T*N] | cursor(+pad)[4] | offs[T*N] | eid[T*E] | rank[T*E]
  //            then bf16: wt[5*D*D] | xb[N*D]
  int* cnt    = (int*)d_ws;
  int* cursor = cnt + T * N;
  int* offs   = cursor + 4;
  int* eid    = offs + T * N;
  int* rank   = eid + T * E;   // rank doubles as slack for eid's +1 prefetch
  __bf16* wt  = (__bf16*)(rank + T * E);
  __bf16* xb  = wt + 5 * D * D;

  const size_t need_xb =
      (size_t)(T * N + 4 + T * N + T * E + T * E) * 4 + (size_t)5 * D * D * 2 +
      (size_t)N * D * 2;
  const bool use_xb = ws_size >= need_xb;

  k_zero<<<(T * N + 4 + 255) / 256, 256, 0, stream>>>(cnt, T * N + 4);
  if (use_xb) {
    k_prep<true><<<CNT_B + PX_B + PW_B, 256, 0, stream>>>(dst, cnt, rank, x, xb,
                                                          W, Wself, wt);
  } else {
    k_prep<false><<<CNT_B + PW_B, 256, 0, stream>>>(dst, cnt, rank, x, xb, W,
                                                    Wself, wt);
  }
  k_offsets<<<(T * N + 255) / 256, 256, 0, stream>>>(cnt, offs, cursor);
  k_scatter<<<(T * E + 255) / 256, 256, 0, stream>>>(src, dst, offs, rank, eid);
  if (use_xb) {
    k_fused<true><<<N / NT, 256, 0, stream>>>(x, xb, wt, b, bself, cnt, offs,
                                              eid, out);
  } else {
    k_fused<false><<<N / NT, 256, 0, stream>>>(x, xb, wt, b, bself, cnt, offs,
                                               eid, out);
  }
}